// Round 5
// baseline (382.567 us; speedup 1.0000x reference)
//
#include <hip/hip_runtime.h>
#include <stdint.h>

#define NB 8
#define CC 512
#define LL 3136
#define CIN 256

typedef __attribute__((ext_vector_type(8))) short bf8;
typedef __attribute__((ext_vector_type(4))) float f4;
typedef __attribute__((ext_vector_type(16))) float f16v;

__device__ __forceinline__ f4 mfma_bf16(bf8 a, bf8 b, f4 c) {
  return __builtin_amdgcn_mfma_f32_16x16x32_bf16(a, b, c, 0, 0, 0);
}

__device__ __forceinline__ f16v mfma32(bf8 a, bf8 b, f16v c) {
  return __builtin_amdgcn_mfma_f32_32x32x16_bf16(a, b, c, 0, 0, 0);
}

__device__ __forceinline__ unsigned short f2bf(float f) {
  unsigned int u = __float_as_uint(f);
  u += 0x7FFFu + ((u >> 16) & 1u);
  return (unsigned short)(u >> 16);
}

__device__ __forceinline__ void gload_lds16(const unsigned short* g, unsigned short* l) {
  __builtin_amdgcn_global_load_lds(
      (const __attribute__((address_space(1))) void*)g,
      (__attribute__((address_space(3))) void*)l, 16, 0, 0);
}

// ---- kernel 0a: convert weights to bf16. layout: [Wth][Wph][Wg][Wout]
__global__ void k_convw(const float* Wth, const float* Wph, const float* Wg, const float* Wout,
                        unsigned short* dst) {
  int i = blockIdx.x * 256 + threadIdx.x;
  int which = i >> 17;
  int off = i & 131071;
  const float* s = which == 0 ? Wth : which == 1 ? Wph : which == 2 ? Wg : Wout;
  dst[i] = f2bf(s[off]);
}

// ---- kernel 0b: transpose x (n,C,L) fp32 -> xT (n,L,C) bf16, 64x64 tiles
__global__ __launch_bounds__(256) void k_xT(const float* x, unsigned short* xT) {
  __shared__ unsigned short tile[64][66];
  const int lt = blockIdx.x, n = blockIdx.y, ct = blockIdx.z;
  const int t = threadIdx.x;
  const float* xb = x + (size_t)n * CC * LL + (size_t)(ct * 64) * LL + lt * 64;
  const int tl = t & 63, trow = t >> 6;
#pragma unroll
  for (int i = 0; i < 16; ++i) {
    int c = i * 4 + trow;
    tile[c][tl] = f2bf(xb[(size_t)c * LL + tl]);
  }
  __syncthreads();
  unsigned short* xo = xT + (size_t)n * LL * CC + (size_t)(lt * 64) * CC + ct * 64;
  const int tc = t & 63, lrow = t >> 6;
#pragma unroll
  for (int i = 0; i < 16; ++i) {
    int l = i * 4 + lrow;
    xo[(size_t)l * CC + tc] = tile[tc][l];
  }
}

// ---- kernel 1 v2: projections, LDS-staged GEMM (unchanged from R4).
__global__ __launch_bounds__(256, 3) void k_proj(const unsigned short* Wbf,
    const float* bth, const float* bph, const float* bg,
    const unsigned short* xT, unsigned short* QT, unsigned short* KT, unsigned short* Vb) {
  __shared__ unsigned short wtile[2][8192];
  __shared__ unsigned short xtile[2][4096];
  const int bid = blockIdx.x;
  const int n = bid & 7, t = bid >> 3;
  const int lt = t % 49, z = t / 49;
  const int proj = z >> 1, cith = z & 1;
  const int tid = threadIdx.x;
  const int wave = tid >> 6, lane = tid & 63;
  const int quad = lane >> 4, c16 = lane & 15;

  const unsigned short* Wg = Wbf + proj * 131072 + (size_t)(cith * 128) * CC;
  const unsigned short* Xg = xT + (size_t)n * LL * CC + (size_t)(lt * 64) * CC;

  auto issue = [&](int chunk, int b) {
    const int cb = chunk * 64;
#pragma unroll
    for (int i = 0; i < 4; ++i) {
      int seg = i * 4 + wave;
      int p = seg * 64 + lane;
      int r = p >> 3, sl = p & 7, g = sl ^ (r & 7);
      gload_lds16(Wg + (size_t)r * CC + cb + g * 8, &wtile[b][seg * 512]);
    }
#pragma unroll
    for (int i = 0; i < 2; ++i) {
      int seg = i * 4 + wave;
      int p = seg * 64 + lane;
      int r = p >> 3, sl = p & 7, g = sl ^ (r & 7);
      gload_lds16(Xg + (size_t)r * CC + cb + g * 8, &xtile[b][seg * 512]);
    }
  };

  const f4 zz = {0.f, 0.f, 0.f, 0.f};
  f4 acc[2][4];
#pragma unroll
  for (int i = 0; i < 2; ++i)
#pragma unroll
    for (int j = 0; j < 4; ++j) acc[i][j] = zz;

  issue(0, 0);
  for (int chunk = 0; chunk < 8; ++chunk) {
    __syncthreads();
    if (chunk + 1 < 8) issue(chunk + 1, (chunk + 1) & 1);
    const int bb = chunk & 1;
#pragma unroll
    for (int kc = 0; kc < 2; ++kc) {
      const int slot = (kc * 4 + quad) ^ (c16 & 7);
      bf8 wf[2], xf[4];
#pragma unroll
      for (int sub = 0; sub < 2; ++sub)
        wf[sub] = *(const bf8*)(&wtile[bb][(wave * 32 + sub * 16 + c16) * 64 + slot * 8]);
#pragma unroll
      for (int nt = 0; nt < 4; ++nt)
        xf[nt] = *(const bf8*)(&xtile[bb][(nt * 16 + c16) * 64 + slot * 8]);
      if (proj < 2) {
#pragma unroll
        for (int sub = 0; sub < 2; ++sub)
#pragma unroll
          for (int nt = 0; nt < 4; ++nt)
            acc[sub][nt] = mfma_bf16(wf[sub], xf[nt], acc[sub][nt]);
      } else {
#pragma unroll
        for (int sub = 0; sub < 2; ++sub)
#pragma unroll
          for (int nt = 0; nt < 4; ++nt)
            acc[sub][nt] = mfma_bf16(xf[nt], wf[sub], acc[sub][nt]);
      }
    }
  }

  if (proj < 2) {
    const float* bias = proj == 0 ? bth : bph;
    unsigned short* dst = proj == 0 ? QT : KT;
#pragma unroll
    for (int sub = 0; sub < 2; ++sub) {
      const int ciB = cith * 128 + wave * 32 + sub * 16 + quad * 4;
      const float b0 = bias[ciB + 0], b1 = bias[ciB + 1];
      const float b2 = bias[ciB + 2], b3 = bias[ciB + 3];
#pragma unroll
      for (int nt = 0; nt < 4; ++nt) {
        int l = lt * 64 + nt * 16 + c16;
        ushort4 v;
        v.x = f2bf(acc[sub][nt][0] + b0);
        v.y = f2bf(acc[sub][nt][1] + b1);
        v.z = f2bf(acc[sub][nt][2] + b2);
        v.w = f2bf(acc[sub][nt][3] + b3);
        *(ushort4*)(dst + ((size_t)n * LL + l) * CIN + ciB) = v;
      }
    }
  } else {
#pragma unroll
    for (int sub = 0; sub < 2; ++sub) {
      const int ci = cith * 128 + wave * 32 + sub * 16 + c16;
      const float bv = bg[ci];
#pragma unroll
      for (int nt = 0; nt < 4; ++nt) {
        int l = lt * 64 + nt * 16 + quad * 4;
        ushort4 v;
        v.x = f2bf(acc[sub][nt][0] + bv);
        v.y = f2bf(acc[sub][nt][1] + bv);
        v.z = f2bf(acc[sub][nt][2] + bv);
        v.w = f2bf(acc[sub][nt][3] + bv);
        *(ushort4*)(Vb + ((size_t)n * CIN + ci) * LL + l) = v;
      }
    }
  }
}

// ---- kernel 2 v4: flash attention, 32x32x16 MFMA.
// 4 waves x 32 queries = 128 q/block; grid 200 (8 imgs x 25, tail clamped).
// K,V staged in LDS (async dbuf, same swizzles as R4); each wave reads each staged
// byte exactly once -> LDS bytes/FLOP halved vs 16x16. Softmax denom recovered from
// the P A-fragment readback (1 VGPR), reduced once at the end.
__global__ __launch_bounds__(256, 2) void k_attn(const unsigned short* QT, const unsigned short* KT,
                                                 const unsigned short* Vb, unsigned short* O) {
  __shared__ unsigned short kbuf[2][8192];   // 32 keys x 512B rows, granule slot = g ^ row
  __shared__ unsigned short vbuf[2][8192];   // 256 ci x 64B rows, slot = g ^ ((row>>1)&3)
  __shared__ __align__(16) unsigned short plds[4][1280];   // per wave: 32 rows x 40 shorts
  const int bid = blockIdx.x;          // n = bid&7 -> XCD L2 locality
  const int n = bid & 7, qb = bid >> 3;
  const int tid = threadIdx.x;
  const int wave = tid >> 6, lane = tid & 63;
  const int l31 = lane & 31, half = lane >> 5;
  int q0 = qb * 128 + wave * 32;
  const bool do_store = q0 < LL;
  if (q0 > LL - 32) q0 = LL - 32;      // tail block: waves 2,3 duplicate (masked store)
  const unsigned short* Qb = QT + ((size_t)n * LL + q0) * CIN;
  const unsigned short* Kbase = KT + (size_t)n * LL * CIN;
  const unsigned short* Vbase = Vb + (size_t)n * CIN * LL;

  // Q fragments (A-layout: m=l31, k=kc*16+half*8+j), softmax scale folded
  const float qs = 0.09016844005556021f;   // log2(e)/16
  bf8 qf[16];
#pragma unroll
  for (int kc = 0; kc < 16; ++kc) {
    bf8 q = *(const bf8*)(Qb + (size_t)l31 * CIN + kc * 16 + half * 8);
#pragma unroll
    for (int e = 0; e < 8; ++e) {
      float f = __uint_as_float(((unsigned)(unsigned short)q[e]) << 16) * qs;
      q[e] = (short)f2bf(f);
    }
    qf[kc] = q;
  }

  f16v o[8];
#pragma unroll
  for (int t = 0; t < 8; ++t)
#pragma unroll
    for (int r = 0; r < 16; ++r) o[t][r] = 0.f;
  float sden = 0.f;   // per-lane partial denominator for q-row l31 (half k-range)

  auto issue = [&](int kt, int b) {
    const int k0 = kt * 32;
    const unsigned short* Kg = Kbase + (size_t)k0 * CIN;
    const unsigned short* Vg = Vbase + k0;
#pragma unroll
    for (int i = 0; i < 4; ++i) {
      int seg = i * 4 + wave;
      int idx = seg * 64 + lane;
      {
        int r = idx >> 5, sl = idx & 31, g = sl ^ r;
        gload_lds16(Kg + r * CIN + g * 8, &kbuf[b][seg * 512]);
      }
      {
        int r = idx >> 2, sl = idx & 3, g = sl ^ ((r >> 1) & 3);
        gload_lds16(Vg + (size_t)r * LL + g * 8, &vbuf[b][seg * 512]);
      }
    }
  };

  unsigned short* pw = &plds[wave][0];
  issue(0, 0);
  for (int kt = 0; kt < 98; ++kt) {
    __syncthreads();                   // tile kt resident; prev compute done
    if (kt + 1 < 98) issue(kt + 1, (kt + 1) & 1);
    const int b = kt & 1;
    const unsigned short* kb = &kbuf[b][0];
    const unsigned short* vbp = &vbuf[b][0];

    // S = Q K^T : B-frag key=l31, ci granule g = kc*2+half, slot = g ^ l31
    f16v sc;
#pragma unroll
    for (int r = 0; r < 16; ++r) sc[r] = 0.f;
#pragma unroll
    for (int kc = 0; kc < 16; ++kc) {
      int slot = (kc * 2 + half) ^ l31;
      bf8 bfr = *(const bf8*)(kb + l31 * 256 + slot * 8);
      sc = mfma32(qf[kc], bfr, sc);
    }
    // P = exp2(S) -> plds (C-layout row = (r&3)+8*(r>>2)+4*half, col = l31)
#pragma unroll
    for (int r = 0; r < 16; ++r) {
      float p = __builtin_amdgcn_exp2f(sc[r]);
      int row = (r & 3) + 8 * (r >> 2) + 4 * half;
      pw[row * 40 + l31] = f2bf(p);
    }
    // A-frag readback (row = l31) + denominator accumulation
    bf8 af[2];
#pragma unroll
    for (int kc2 = 0; kc2 < 2; ++kc2) {
      af[kc2] = *(const bf8*)(pw + l31 * 40 + kc2 * 16 + half * 8);
#pragma unroll
      for (int e = 0; e < 8; ++e)
        sden += __uint_as_float(((unsigned)(unsigned short)af[kc2][e]) << 16);
    }
    // O += P V : V row = t*32+l31, granule g = kc2*2+half, slot = g ^ ((l31>>1)&3)
#pragma unroll
    for (int t = 0; t < 8; ++t) {
#pragma unroll
      for (int kc2 = 0; kc2 < 2; ++kc2) {
        int slot = (kc2 * 2 + half) ^ ((l31 >> 1) & 3);
        bf8 v = *(const bf8*)(vbp + (t * 32 + l31) * 32 + slot * 8);
        o[t] = mfma32(af[kc2], v, o[t]);
      }
    }
  }

  // finalize denominator: combine the two k-halves; lane l holds denom for row l31
  sden += __shfl_xor(sden, 32);
  sden = 1.f / sden;
  float inv[16];
#pragma unroll
  for (int r = 0; r < 16; ++r) {
    int row = (r & 3) + 8 * (r >> 2) + 4 * half;
    inv[r] = __shfl(sden, row);
  }

  if (do_store) {
    unsigned short* Ob = O + ((size_t)n * LL + q0) * CIN;
#pragma unroll
    for (int t = 0; t < 8; ++t)
#pragma unroll
      for (int r = 0; r < 16; ++r) {
        int row = (r & 3) + 8 * (r >> 2) + 4 * half;
        Ob[(size_t)row * CIN + t * 32 + l31] = f2bf(o[t][r] * inv[r]);
      }
  }
}

// ---- kernel 3 v2: out = x + b_out + W_out @ y (unchanged from R4).
__global__ __launch_bounds__(256, 3) void k_out(const unsigned short* O, const unsigned short* Wo,
    const float* bout, const float* x, float* out) {
  __shared__ unsigned short wtile[2][8192];
  __shared__ unsigned short otile[2][4096];
  const int bid = blockIdx.x;
  const int n = bid & 7, t = bid >> 3;
  const int lt = t % 49, cth = t / 49;
  const int tid = threadIdx.x;
  const int wave = tid >> 6, lane = tid & 63;
  const int quad = lane >> 4, c16 = lane & 15;

  const unsigned short* Wg = Wo + (size_t)(cth * 128) * CIN;
  const unsigned short* Og = O + ((size_t)n * LL + lt * 64) * CIN;

  auto issue = [&](int chunk, int b) {
    const int cb = chunk * 64;
#pragma unroll
    for (int i = 0; i < 4; ++i) {
      int seg = i * 4 + wave;
      int p = seg * 64 + lane;
      int r = p >> 3, sl = p & 7, g = sl ^ (r & 7);
      gload_lds16(Wg + (size_t)r * CIN + cb + g * 8, &wtile[b][seg * 512]);
    }
#pragma unroll
    for (int i = 0; i < 2; ++i) {
      int seg = i * 4 + wave;
      int p = seg * 64 + lane;
      int r = p >> 3, sl = p & 7, g = sl ^ (r & 7);
      gload_lds16(Og + (size_t)r * CIN + cb + g * 8, &otile[b][seg * 512]);
    }
  };

  const f4 zz = {0.f, 0.f, 0.f, 0.f};
  f4 acc[4][2];
#pragma unroll
  for (int i = 0; i < 4; ++i)
#pragma unroll
    for (int j = 0; j < 2; ++j) acc[i][j] = zz;

  issue(0, 0);
  for (int chunk = 0; chunk < 4; ++chunk) {
    __syncthreads();
    if (chunk + 1 < 4) issue(chunk + 1, (chunk + 1) & 1);
    const int bb = chunk & 1;
#pragma unroll
    for (int kc = 0; kc < 2; ++kc) {
      const int slot = (kc * 4 + quad) ^ (c16 & 7);
      bf8 wf[2], ofr[4];
#pragma unroll
      for (int sub = 0; sub < 2; ++sub)
        wf[sub] = *(const bf8*)(&wtile[bb][(wave * 32 + sub * 16 + c16) * 64 + slot * 8]);
#pragma unroll
      for (int nt = 0; nt < 4; ++nt)
        ofr[nt] = *(const bf8*)(&otile[bb][(nt * 16 + c16) * 64 + slot * 8]);
#pragma unroll
      for (int nt = 0; nt < 4; ++nt)
#pragma unroll
        for (int sub = 0; sub < 2; ++sub)
          acc[nt][sub] = mfma_bf16(ofr[nt], wf[sub], acc[nt][sub]);
    }
  }

#pragma unroll
  for (int sub = 0; sub < 2; ++sub) {
    const int c = cth * 128 + wave * 32 + sub * 16 + c16;
    const float bv = bout[c];
#pragma unroll
    for (int nt = 0; nt < 4; ++nt) {
      int l = lt * 64 + nt * 16 + quad * 4;
      size_t base = ((size_t)n * CC + c) * LL + l;
      f4 xv = *(const f4*)(x + base);
      f4 r;
      r[0] = xv[0] + bv + acc[nt][sub][0];
      r[1] = xv[1] + bv + acc[nt][sub][1];
      r[2] = xv[2] + bv + acc[nt][sub][2];
      r[3] = xv[3] + bv + acc[nt][sub][3];
      *(f4*)(out + base) = r;
    }
  }
}

extern "C" void kernel_launch(void* const* d_in, const int* in_sizes, int n_in,
                              void* d_out, int out_size, void* d_ws, size_t ws_size,
                              hipStream_t stream) {
  const float* x     = (const float*)d_in[0];
  const float* W_g   = (const float*)d_in[1];
  const float* b_g   = (const float*)d_in[2];
  const float* W_th  = (const float*)d_in[3];
  const float* b_th  = (const float*)d_in[4];
  const float* W_ph  = (const float*)d_in[5];
  const float* b_ph  = (const float*)d_in[6];
  const float* W_out = (const float*)d_in[7];
  const float* b_out = (const float*)d_in[8];

  char* ws = (char*)d_ws;
  const size_t SZ_W  = 1048576;
  const size_t SZ_P  = 12845056;
  unsigned short* Wbf = (unsigned short*)(ws);
  unsigned short* QT  = (unsigned short*)(ws + SZ_W);
  unsigned short* KT  = (unsigned short*)(ws + SZ_W + SZ_P);
  unsigned short* Vb  = (unsigned short*)(ws + SZ_W + 2 * SZ_P);
  unsigned short* xT  = (unsigned short*)(ws + SZ_W + 3 * SZ_P);
  unsigned short* O   = xT;  // alias: xT dead after k_proj
  float* out = (float*)d_out;

  k_convw<<<2048, 256, 0, stream>>>(W_th, W_ph, W_g, W_out, Wbf);
  k_xT<<<dim3(49, 8, 8), 256, 0, stream>>>(x, xT);
  k_proj<<<2352, 256, 0, stream>>>(Wbf, b_th, b_ph, b_g, xT, QT, KT, Vb);
  k_attn<<<200, 256, 0, stream>>>(QT, KT, Vb, O);
  k_out<<<1568, 256, 0, stream>>>(O, Wbf + 3 * 131072, b_out, x, out);
}

// Round 6
// 306.676 us; speedup vs baseline: 1.2475x; 1.2475x over previous
//
#include <hip/hip_runtime.h>
#include <stdint.h>

#define NB 8
#define CC 512
#define LL 3136
#define CIN 256

typedef __attribute__((ext_vector_type(8))) short bf8;
typedef __attribute__((ext_vector_type(4))) float f4;
typedef __attribute__((ext_vector_type(16))) float f16v;

__device__ __forceinline__ f4 mfma_bf16(bf8 a, bf8 b, f4 c) {
  return __builtin_amdgcn_mfma_f32_16x16x32_bf16(a, b, c, 0, 0, 0);
}

__device__ __forceinline__ f16v mfma32(bf8 a, bf8 b, f16v c) {
  return __builtin_amdgcn_mfma_f32_32x32x16_bf16(a, b, c, 0, 0, 0);
}

__device__ __forceinline__ unsigned short f2bf(float f) {
  unsigned int u = __float_as_uint(f);
  u += 0x7FFFu + ((u >> 16) & 1u);
  return (unsigned short)(u >> 16);
}

__device__ __forceinline__ void gload_lds16(const unsigned short* g, unsigned short* l) {
  __builtin_amdgcn_global_load_lds(
      (const __attribute__((address_space(1))) void*)g,
      (__attribute__((address_space(3))) void*)l, 16, 0, 0);
}

// ---- kernel 0a: convert weights to bf16. layout: [Wth][Wph][Wg][Wout]
__global__ void k_convw(const float* Wth, const float* Wph, const float* Wg, const float* Wout,
                        unsigned short* dst) {
  int i = blockIdx.x * 256 + threadIdx.x;
  int which = i >> 17;
  int off = i & 131071;
  const float* s = which == 0 ? Wth : which == 1 ? Wph : which == 2 ? Wg : Wout;
  dst[i] = f2bf(s[off]);
}

// ---- kernel 0b: transpose x (n,C,L) fp32 -> xT (n,L,C) bf16, 64x64 tiles
__global__ __launch_bounds__(256) void k_xT(const float* x, unsigned short* xT) {
  __shared__ unsigned short tile[64][66];
  const int lt = blockIdx.x, n = blockIdx.y, ct = blockIdx.z;
  const int t = threadIdx.x;
  const float* xb = x + (size_t)n * CC * LL + (size_t)(ct * 64) * LL + lt * 64;
  const int tl = t & 63, trow = t >> 6;
#pragma unroll
  for (int i = 0; i < 16; ++i) {
    int c = i * 4 + trow;
    tile[c][tl] = f2bf(xb[(size_t)c * LL + tl]);
  }
  __syncthreads();
  unsigned short* xo = xT + (size_t)n * LL * CC + (size_t)(lt * 64) * CC + ct * 64;
  const int tc = t & 63, lrow = t >> 6;
#pragma unroll
  for (int i = 0; i < 16; ++i) {
    int l = i * 4 + lrow;
    xo[(size_t)l * CC + tc] = tile[tc][l];
  }
}

// ---- kernel 1 v2: projections, LDS-staged GEMM (unchanged from R4).
__global__ __launch_bounds__(256, 3) void k_proj(const unsigned short* Wbf,
    const float* bth, const float* bph, const float* bg,
    const unsigned short* xT, unsigned short* QT, unsigned short* KT, unsigned short* Vb) {
  __shared__ unsigned short wtile[2][8192];
  __shared__ unsigned short xtile[2][4096];
  const int bid = blockIdx.x;
  const int n = bid & 7, t = bid >> 3;
  const int lt = t % 49, z = t / 49;
  const int proj = z >> 1, cith = z & 1;
  const int tid = threadIdx.x;
  const int wave = tid >> 6, lane = tid & 63;
  const int quad = lane >> 4, c16 = lane & 15;

  const unsigned short* Wg = Wbf + proj * 131072 + (size_t)(cith * 128) * CC;
  const unsigned short* Xg = xT + (size_t)n * LL * CC + (size_t)(lt * 64) * CC;

  auto issue = [&](int chunk, int b) {
    const int cb = chunk * 64;
#pragma unroll
    for (int i = 0; i < 4; ++i) {
      int seg = i * 4 + wave;
      int p = seg * 64 + lane;
      int r = p >> 3, sl = p & 7, g = sl ^ (r & 7);
      gload_lds16(Wg + (size_t)r * CC + cb + g * 8, &wtile[b][seg * 512]);
    }
#pragma unroll
    for (int i = 0; i < 2; ++i) {
      int seg = i * 4 + wave;
      int p = seg * 64 + lane;
      int r = p >> 3, sl = p & 7, g = sl ^ (r & 7);
      gload_lds16(Xg + (size_t)r * CC + cb + g * 8, &xtile[b][seg * 512]);
    }
  };

  const f4 zz = {0.f, 0.f, 0.f, 0.f};
  f4 acc[2][4];
#pragma unroll
  for (int i = 0; i < 2; ++i)
#pragma unroll
    for (int j = 0; j < 4; ++j) acc[i][j] = zz;

  issue(0, 0);
  for (int chunk = 0; chunk < 8; ++chunk) {
    __syncthreads();
    if (chunk + 1 < 8) issue(chunk + 1, (chunk + 1) & 1);
    const int bb = chunk & 1;
#pragma unroll
    for (int kc = 0; kc < 2; ++kc) {
      const int slot = (kc * 4 + quad) ^ (c16 & 7);
      bf8 wf[2], xf[4];
#pragma unroll
      for (int sub = 0; sub < 2; ++sub)
        wf[sub] = *(const bf8*)(&wtile[bb][(wave * 32 + sub * 16 + c16) * 64 + slot * 8]);
#pragma unroll
      for (int nt = 0; nt < 4; ++nt)
        xf[nt] = *(const bf8*)(&xtile[bb][(nt * 16 + c16) * 64 + slot * 8]);
      if (proj < 2) {
#pragma unroll
        for (int sub = 0; sub < 2; ++sub)
#pragma unroll
          for (int nt = 0; nt < 4; ++nt)
            acc[sub][nt] = mfma_bf16(wf[sub], xf[nt], acc[sub][nt]);
      } else {
#pragma unroll
        for (int sub = 0; sub < 2; ++sub)
#pragma unroll
          for (int nt = 0; nt < 4; ++nt)
            acc[sub][nt] = mfma_bf16(xf[nt], wf[sub], acc[sub][nt]);
      }
    }
  }

  if (proj < 2) {
    const float* bias = proj == 0 ? bth : bph;
    unsigned short* dst = proj == 0 ? QT : KT;
#pragma unroll
    for (int sub = 0; sub < 2; ++sub) {
      const int ciB = cith * 128 + wave * 32 + sub * 16 + quad * 4;
      const float b0 = bias[ciB + 0], b1 = bias[ciB + 1];
      const float b2 = bias[ciB + 2], b3 = bias[ciB + 3];
#pragma unroll
      for (int nt = 0; nt < 4; ++nt) {
        int l = lt * 64 + nt * 16 + c16;
        ushort4 v;
        v.x = f2bf(acc[sub][nt][0] + b0);
        v.y = f2bf(acc[sub][nt][1] + b1);
        v.z = f2bf(acc[sub][nt][2] + b2);
        v.w = f2bf(acc[sub][nt][3] + b3);
        *(ushort4*)(dst + ((size_t)n * LL + l) * CIN + ciB) = v;
      }
    }
  } else {
#pragma unroll
    for (int sub = 0; sub < 2; ++sub) {
      const int ci = cith * 128 + wave * 32 + sub * 16 + c16;
      const float bv = bg[ci];
#pragma unroll
      for (int nt = 0; nt < 4; ++nt) {
        int l = lt * 64 + nt * 16 + quad * 4;
        ushort4 v;
        v.x = f2bf(acc[sub][nt][0] + bv);
        v.y = f2bf(acc[sub][nt][1] + bv);
        v.z = f2bf(acc[sub][nt][2] + bv);
        v.w = f2bf(acc[sub][nt][3] + bv);
        *(ushort4*)(Vb + ((size_t)n * CIN + ci) * LL + l) = v;
      }
    }
  }
}

// ---- kernel 2 v6: flash attention, 32x32x16 MFMA + global 2-way key split.
// grid 400: n=bid&7, ks=(bid>>3)&1, qb=bid>>4 (25 q-blocks of 128 q).
// Each block does 49 key-tiles of 32 keys; writes UNNORMALIZED O partial (bf16)
// + per-row denominator (fp32). k_den + k_out epilogue finish the softmax divide.
__global__ __launch_bounds__(256, 2) void k_attn(const unsigned short* QT, const unsigned short* KT,
                                                 const unsigned short* Vb, unsigned short* Opart,
                                                 float* denp) {
  __shared__ unsigned short kbuf[2][8192];   // 32 keys x 256 shorts, granule slot = g ^ row
  __shared__ unsigned short vbuf[2][8192];   // 256 ci x 32 shorts, slot = g ^ ((row>>1)&3)
  __shared__ __align__(16) unsigned short plds[4][1280];   // per wave: 32 rows x 40 shorts
  const int bid = blockIdx.x;
  const int n = bid & 7, ks = (bid >> 3) & 1, qb = bid >> 4;
  const int tid = threadIdx.x;
  const int wave = tid >> 6, lane = tid & 63;
  const int l31 = lane & 31, half = lane >> 5;
  int q0 = qb * 128 + wave * 32;
  const bool do_store = q0 < LL;
  if (q0 > LL - 32) q0 = LL - 32;      // tail: waves 2,3 duplicate wave-1 rows, stores masked
  const unsigned short* Qb = QT + ((size_t)n * LL + q0) * CIN;
  const unsigned short* Kks = KT + (size_t)n * LL * CIN + (size_t)(ks * 49 * 32) * CIN;
  const unsigned short* Vks = Vb + (size_t)n * CIN * LL + ks * 49 * 32;

  // Q fragments (A-layout: m=l31, k=kc*16+half*8+j), softmax scale folded
  const float qs = 0.09016844005556021f;   // log2(e)/16
  bf8 qf[16];
#pragma unroll
  for (int kc = 0; kc < 16; ++kc) {
    bf8 q = *(const bf8*)(Qb + (size_t)l31 * CIN + kc * 16 + half * 8);
#pragma unroll
    for (int e = 0; e < 8; ++e) {
      float f = __uint_as_float(((unsigned)(unsigned short)q[e]) << 16) * qs;
      q[e] = (short)f2bf(f);
    }
    qf[kc] = q;
  }

  f16v o[8];
#pragma unroll
  for (int t = 0; t < 8; ++t)
#pragma unroll
    for (int r = 0; r < 16; ++r) o[t][r] = 0.f;
  float sden = 0.f;   // per-lane partial denominator for q-row l31 (this lane's k-half)

  auto issue = [&](int kt, int b) {
    const int k0 = kt * 32;
    const unsigned short* Kg = Kks + (size_t)k0 * CIN;
    const unsigned short* Vg = Vks + k0;
#pragma unroll
    for (int i = 0; i < 4; ++i) {
      int seg = i * 4 + wave;
      int idx = seg * 64 + lane;
      {
        int r = idx >> 5, sl = idx & 31, g = sl ^ r;
        gload_lds16(Kg + r * CIN + g * 8, &kbuf[b][seg * 512]);
      }
      {
        int r = idx >> 2, sl = idx & 3, g = sl ^ ((r >> 1) & 3);
        gload_lds16(Vg + (size_t)r * LL + g * 8, &vbuf[b][seg * 512]);
      }
    }
  };

  unsigned short* pw = &plds[wave][0];
  issue(0, 0);
  for (int kt = 0; kt < 49; ++kt) {
    __syncthreads();                   // tile kt resident; prev compute done
    if (kt + 1 < 49) issue(kt + 1, (kt + 1) & 1);
    const int b = kt & 1;
    const unsigned short* kb = &kbuf[b][0];
    const unsigned short* vbp = &vbuf[b][0];

    // S = Q K^T : B-frag key=l31, ci granule g = kc*2+half, slot = g ^ l31
    f16v sc;
#pragma unroll
    for (int r = 0; r < 16; ++r) sc[r] = 0.f;
#pragma unroll
    for (int kc = 0; kc < 16; ++kc) {
      int slot = (kc * 2 + half) ^ l31;
      bf8 bfr = *(const bf8*)(kb + l31 * 256 + slot * 8);
      sc = mfma32(qf[kc], bfr, sc);
    }
    // P = exp2(S) -> plds (C-layout row = (r&3)+8*(r>>2)+4*half, col = l31)
#pragma unroll
    for (int r = 0; r < 16; ++r) {
      float p = __builtin_amdgcn_exp2f(sc[r]);
      int row = (r & 3) + 8 * (r >> 2) + 4 * half;
      pw[row * 40 + l31] = f2bf(p);
    }
    // A-frag readback (row = l31) + denominator accumulation
    bf8 af[2];
#pragma unroll
    for (int kc2 = 0; kc2 < 2; ++kc2) {
      af[kc2] = *(const bf8*)(pw + l31 * 40 + kc2 * 16 + half * 8);
#pragma unroll
      for (int e = 0; e < 8; ++e)
        sden += __uint_as_float(((unsigned)(unsigned short)af[kc2][e]) << 16);
    }
    // O += P V : V row = t*32+l31, granule g = kc2*2+half, slot = g ^ ((l31>>1)&3)
#pragma unroll
    for (int t = 0; t < 8; ++t) {
#pragma unroll
      for (int kc2 = 0; kc2 < 2; ++kc2) {
        int slot = (kc2 * 2 + half) ^ ((l31 >> 1) & 3);
        bf8 v = *(const bf8*)(vbp + (t * 32 + l31) * 32 + slot * 8);
        o[t] = mfma32(af[kc2], v, o[t]);
      }
    }
  }

  // combine the two k-halves of the denominator; lane l31 (both halves) holds den[row l31]
  sden += __shfl_xor(sden, 32);

  if (do_store) {
    if (lane < 32) denp[((size_t)ks * NB + n) * LL + q0 + l31] = sden;
    unsigned short* Ob = Opart + (((size_t)ks * NB + n) * LL + q0) * CIN;
#pragma unroll
    for (int t = 0; t < 8; ++t)
#pragma unroll
      for (int r = 0; r < 16; ++r) {
        int row = (r & 3) + 8 * (r >> 2) + 4 * half;
        Ob[(size_t)row * CIN + t * 32 + l31] = f2bf(o[t][r]);
      }
  }
}

// ---- kernel 2b: invden = 1/(den0+den1), NB*LL elements
__global__ void k_den(const float* denp, float* invden) {
  int i = blockIdx.x * 256 + threadIdx.x;
  if (i < NB * LL) invden[i] = 1.f / (denp[i] + denp[NB * LL + i]);
}

// ---- kernel 3 v3: out = x + b_out + Wout @ ((O0+O1)*invden).
// K-reduction extended to 8 chunks: chunks 0-3 read O0, 4-7 read O1 (same Wout cols);
// invden folded into the epilogue (C row = l).
__global__ __launch_bounds__(256, 3) void k_out(const unsigned short* O0, const unsigned short* O1,
    const unsigned short* Wo, const float* bout, const float* invden,
    const float* x, float* out) {
  __shared__ unsigned short wtile[2][8192];
  __shared__ unsigned short otile[2][4096];
  const int bid = blockIdx.x;
  const int n = bid & 7, t = bid >> 3;
  const int lt = t % 49, cth = t / 49;
  const int tid = threadIdx.x;
  const int wave = tid >> 6, lane = tid & 63;
  const int quad = lane >> 4, c16 = lane & 15;

  const unsigned short* Wg = Wo + (size_t)(cth * 128) * CIN;
  const unsigned short* Og0 = O0 + ((size_t)n * LL + lt * 64) * CIN;
  const unsigned short* Og1 = O1 + ((size_t)n * LL + lt * 64) * CIN;

  auto issue = [&](int chunk, int b) {
    const int cb = (chunk & 3) * 64;
    const unsigned short* Og = chunk < 4 ? Og0 : Og1;
#pragma unroll
    for (int i = 0; i < 4; ++i) {
      int seg = i * 4 + wave;
      int p = seg * 64 + lane;
      int r = p >> 3, sl = p & 7, g = sl ^ (r & 7);
      gload_lds16(Wg + (size_t)r * CIN + cb + g * 8, &wtile[b][seg * 512]);
    }
#pragma unroll
    for (int i = 0; i < 2; ++i) {
      int seg = i * 4 + wave;
      int p = seg * 64 + lane;
      int r = p >> 3, sl = p & 7, g = sl ^ (r & 7);
      gload_lds16(Og + (size_t)r * CIN + cb + g * 8, &otile[b][seg * 512]);
    }
  };

  const f4 zz = {0.f, 0.f, 0.f, 0.f};
  f4 acc[4][2];
#pragma unroll
  for (int i = 0; i < 4; ++i)
#pragma unroll
    for (int j = 0; j < 2; ++j) acc[i][j] = zz;

  issue(0, 0);
  for (int chunk = 0; chunk < 8; ++chunk) {
    __syncthreads();
    if (chunk + 1 < 8) issue(chunk + 1, (chunk + 1) & 1);
    const int bb = chunk & 1;
#pragma unroll
    for (int kc = 0; kc < 2; ++kc) {
      const int slot = (kc * 4 + quad) ^ (c16 & 7);
      bf8 wf[2], ofr[4];
#pragma unroll
      for (int sub = 0; sub < 2; ++sub)
        wf[sub] = *(const bf8*)(&wtile[bb][(wave * 32 + sub * 16 + c16) * 64 + slot * 8]);
#pragma unroll
      for (int nt = 0; nt < 4; ++nt)
        ofr[nt] = *(const bf8*)(&otile[bb][(nt * 16 + c16) * 64 + slot * 8]);
#pragma unroll
      for (int nt = 0; nt < 4; ++nt)
#pragma unroll
        for (int sub = 0; sub < 2; ++sub)
          acc[nt][sub] = mfma_bf16(ofr[nt], wf[sub], acc[nt][sub]);
    }
  }

#pragma unroll
  for (int sub = 0; sub < 2; ++sub) {
    const int c = cth * 128 + wave * 32 + sub * 16 + c16;
    const float bv = bout[c];
#pragma unroll
    for (int nt = 0; nt < 4; ++nt) {
      int l = lt * 64 + nt * 16 + quad * 4;
      f4 iv = *(const f4*)(invden + (size_t)n * LL + l);
      size_t base = ((size_t)n * CC + c) * LL + l;
      f4 xv = *(const f4*)(x + base);
      f4 r;
      r[0] = xv[0] + bv + acc[nt][sub][0] * iv[0];
      r[1] = xv[1] + bv + acc[nt][sub][1] * iv[1];
      r[2] = xv[2] + bv + acc[nt][sub][2] * iv[2];
      r[3] = xv[3] + bv + acc[nt][sub][3] * iv[3];
      *(f4*)(out + base) = r;
    }
  }
}

extern "C" void kernel_launch(void* const* d_in, const int* in_sizes, int n_in,
                              void* d_out, int out_size, void* d_ws, size_t ws_size,
                              hipStream_t stream) {
  const float* x     = (const float*)d_in[0];
  const float* W_g   = (const float*)d_in[1];
  const float* b_g   = (const float*)d_in[2];
  const float* W_th  = (const float*)d_in[3];
  const float* b_th  = (const float*)d_in[4];
  const float* W_ph  = (const float*)d_in[5];
  const float* b_ph  = (const float*)d_in[6];
  const float* W_out = (const float*)d_in[7];
  const float* b_out = (const float*)d_in[8];

  char* ws = (char*)d_ws;
  const size_t SZ_W  = 1048576;            // 4 x 131072 bf16
  const size_t SZ_P  = 12845056;           // 8*3136*256*2 bytes
  unsigned short* Wbf = (unsigned short*)(ws);
  unsigned short* QT  = (unsigned short*)(ws + SZ_W);
  unsigned short* KT  = (unsigned short*)(ws + SZ_W + SZ_P);
  unsigned short* Vb  = (unsigned short*)(ws + SZ_W + 2 * SZ_P);
  unsigned short* xT  = (unsigned short*)(ws + SZ_W + 3 * SZ_P);   // 2*SZ_P bytes
  unsigned short* O0  = xT;                 // alias: xT dead after k_proj
  unsigned short* O1  = (unsigned short*)(ws + SZ_W + 4 * SZ_P);
  float* denp   = (float*)(ws + SZ_W + 5 * SZ_P);                  // 2*NB*LL fp32
  float* invden = (float*)(ws + SZ_W + 5 * SZ_P + 2 * NB * LL * 4);
  float* out = (float*)d_out;

  k_convw<<<2048, 256, 0, stream>>>(W_th, W_ph, W_g, W_out, Wbf);
  k_xT<<<dim3(49, 8, 8), 256, 0, stream>>>(x, xT);
  k_proj<<<2352, 256, 0, stream>>>(Wbf, b_th, b_ph, b_g, xT, QT, KT, Vb);
  k_attn<<<400, 256, 0, stream>>>(QT, KT, Vb, O0, denp);
  k_den<<<98, 256, 0, stream>>>(denp, invden);
  k_out<<<1568, 256, 0, stream>>>(O0, O1, Wbf + 3 * 131072, b_out, invden, x, out);
}